// Round 6
// baseline (208.679 us; speedup 1.0000x reference)
//
#include <hip/hip_runtime.h>

#define BATCH 8192
#define LOSC  2048.0f
#define LOINV (1.0f / 2048.0f)

typedef _Float16 f16x8 __attribute__((ext_vector_type(8)));
typedef __fp16   fp16x2 __attribute__((ext_vector_type(2)));
typedef float    f32x4 __attribute__((ext_vector_type(4)));

union PK2 { fp16x2 h; unsigned u; };
union U8  { f16x8 v; unsigned u[4]; };

// pack two f32 -> one reg of 2 f16 via v_cvt_pkrtz (RTZ is fine for hi/lo
// splitting: any hi with |v-hi| <= ulp works; lo carries the remainder)
__device__ __forceinline__ unsigned pkrtz(float a, float b) {
    PK2 p; p.h = __builtin_amdgcn_cvt_pkrtz(a, b); return p.u;
}
__device__ __forceinline__ float lo0(unsigned hp, float v) {
    PK2 p; p.u = hp; return (v - (float)p.h[0]) * LOSC;
}
__device__ __forceinline__ float lo1(unsigned hp, float v) {
    PK2 p; p.u = hp; return (v - (float)p.h[1]) * LOSC;
}

// ---------------------------------------------------------------------------
// Kernel 1: exact NN (CD=1). Reference distance sqrt(fl(dx*dx)) == |dx| in
// correctly-rounded fp32 -> compare fabsf(dx); first-index argmin preserved
// (strict < over ascending j), self excluded.
// ---------------------------------------------------------------------------
__global__ __launch_bounds__(256) void nn_kernel(const float* __restrict__ c,
                                                 float* __restrict__ c0) {
    __shared__ float cs[BATCH];
    const int t = threadIdx.x;
    {
        const float4* cg = (const float4*)c;
        float4* cl = (float4*)cs;
        for (int j = t; j < BATCH / 4; j += 256) cl[j] = cg[j];
    }
    __syncthreads();
    const int part = t & 31;
    const int i    = blockIdx.x * 8 + (t >> 5);
    const float ci = cs[i];
    const int sj0 = ((i & 3) == 0) ? (i >> 2) : -1;
    const int sj1 = ((i & 3) == 1) ? (i >> 2) : -1;
    const int sj2 = ((i & 3) == 2) ? (i >> 2) : -1;
    const int sj3 = ((i & 3) == 3) ? (i >> 2) : -1;
    const float4* cs4 = (const float4*)cs;
    float bd0 = 3e38f, bd1 = 3e38f, bd2 = 3e38f, bd3 = 3e38f;
    int   bj0 = 0,     bj1 = 0,     bj2 = 0,     bj3 = 0;
    #pragma unroll 4
    for (int tt = 0; tt < 64; ++tt) {
        const int jj = part + (tt << 5);
        const float4 v = cs4[jj];
        float d0 = fabsf(ci - v.x);
        float d1 = fabsf(ci - v.y);
        float d2 = fabsf(ci - v.z);
        float d3 = fabsf(ci - v.w);
        if (jj == sj0) d0 = 3e38f;
        if (jj == sj1) d1 = 3e38f;
        if (jj == sj2) d2 = 3e38f;
        if (jj == sj3) d3 = 3e38f;
        if (d0 < bd0) { bd0 = d0; bj0 = jj; }
        if (d1 < bd1) { bd1 = d1; bj1 = jj; }
        if (d2 < bd2) { bd2 = d2; bj2 = jj; }
        if (d3 < bd3) { bd3 = d3; bj3 = jj; }
    }
    float best = bd0; int bestj = bj0 * 4 + 0;
    { const int j1 = bj1 * 4 + 1; if (bd1 < best || (bd1 == best && j1 < bestj)) { best = bd1; bestj = j1; } }
    { const int j2 = bj2 * 4 + 2; if (bd2 < best || (bd2 == best && j2 < bestj)) { best = bd2; bestj = j2; } }
    { const int j3 = bj3 * 4 + 3; if (bd3 < best || (bd3 == best && j3 < bestj)) { best = bd3; bestj = j3; } }
    #pragma unroll
    for (int off = 1; off < 32; off <<= 1) {
        const float od = __shfl_xor(best, off);
        const int   oj = __shfl_xor(bestj, off);
        if (od < best || (od == best && oj < bestj)) { best = od; bestj = oj; }
    }
    if (part == 0) c0[i] = cs[bestj];
}

// ---------------------------------------------------------------------------
// Kernel 2 (v5): 4 samples/wave (cols 4-7/12-15 duplicate samples 0-3) ->
// 2048 waves = 2 waves/SIMD for latency hiding. Split-f16 MFMA (hi/lo,
// lo scaled 2^11). W-hi fragments + pre-masked biases in registers; W-lo as
// per-lane f16x8 LDS fragments (contiguous 16B/lane -> conflict-free b128).
// Compiler-only fence in the loop pins the WL reads (no barrier cost).
// mfma_f32_16x16x32_f16: A[m=lane&15][k=q*8+j], B[k=q*8+j][n=lane&15],
// C/D col=lane&15, row=q*4+reg.
// ---------------------------------------------------------------------------
__global__ __launch_bounds__(64, 2) void solve_kernel(
    const float* __restrict__ x, const float* __restrict__ c0g,
    const float* __restrict__ W1, const float* __restrict__ b1,
    const float* __restrict__ W2, const float* __restrict__ b2,
    const float* __restrict__ W3, const float* __restrict__ b3,
    const float* __restrict__ W4, float* __restrict__ out)
{
    __shared__ __align__(16) f16x8 WL2f[8][64];   // [T*2+ch][lane], 8 KB
    __shared__ __align__(16) f16x8 WL3f[8][64];   // 8 KB

    const int lane = threadIdx.x & 63;
    const int q  = lane >> 4;
    const int cc = lane & 15;
    const bool fwd = (cc < 8);
    const int s = cc & 3;                 // 4 real samples; cols 4-7 duplicate
    const int sbase = blockIdx.x * 4;

    // ---- stage: build hi fragments (regs) + lo fragments (LDS) in one pass ----
    f16x8 W2h[4][2], W3h[4][2];
    #pragma unroll
    for (int T = 0; T < 4; ++T)
        #pragma unroll
        for (int ch = 0; ch < 2; ++ch) {
            const float* p2 = W2 + (T * 16 + cc) * 64 + ch * 32 + q * 8;
            const float* p3 = W3 + (T * 16 + cc) * 64 + ch * 32 + q * 8;
            const float4 a2 = *(const float4*)p2, b2v = *(const float4*)(p2 + 4);
            const float4 a3 = *(const float4*)p3, b3v = *(const float4*)(p3 + 4);
            U8 h2, l2, h3, l3;
            h2.u[0] = pkrtz(a2.x, a2.y); h2.u[1] = pkrtz(a2.z, a2.w);
            h2.u[2] = pkrtz(b2v.x, b2v.y); h2.u[3] = pkrtz(b2v.z, b2v.w);
            l2.u[0] = pkrtz(lo0(h2.u[0], a2.x), lo1(h2.u[0], a2.y));
            l2.u[1] = pkrtz(lo0(h2.u[1], a2.z), lo1(h2.u[1], a2.w));
            l2.u[2] = pkrtz(lo0(h2.u[2], b2v.x), lo1(h2.u[2], b2v.y));
            l2.u[3] = pkrtz(lo0(h2.u[3], b2v.z), lo1(h2.u[3], b2v.w));
            h3.u[0] = pkrtz(a3.x, a3.y); h3.u[1] = pkrtz(a3.z, a3.w);
            h3.u[2] = pkrtz(b3v.x, b3v.y); h3.u[3] = pkrtz(b3v.z, b3v.w);
            l3.u[0] = pkrtz(lo0(h3.u[0], a3.x), lo1(h3.u[0], a3.y));
            l3.u[1] = pkrtz(lo0(h3.u[1], a3.z), lo1(h3.u[1], a3.w));
            l3.u[2] = pkrtz(lo0(h3.u[2], b3v.x), lo1(h3.u[2], b3v.y));
            l3.u[3] = pkrtz(lo0(h3.u[3], b3v.z), lo1(h3.u[3], b3v.w));
            W2h[T][ch] = h2.v;
            W3h[T][ch] = h3.v;
            WL2f[T * 2 + ch][lane] = l2.v;
            WL3f[T * 2 + ch][lane] = l3.v;
        }

    // ---- pre-masked biases + W4 rows (C-layout rows T*16 + q*4 + r) ----
    float b2m[16], b3m[16], w4r[16];
    #pragma unroll
    for (int T = 0; T < 4; ++T)
        #pragma unroll
        for (int r = 0; r < 4; ++r) {
            const int row = T * 16 + q * 4 + r;
            b2m[T * 4 + r] = fwd ? b2[row] : 0.f;
            b3m[T * 4 + r] = fwd ? b3[row] : 0.f;
            w4r[T * 4 + r] = W4[row];
        }

    // ---- layer-1 constants: rows k = ch*32 + q*8 + j, this lane's sample ----
    float A1v[16], w11v[16];
    {
        const float xs  = x[sbase + s];
        const float c0s = c0g[sbase + s];
        #pragma unroll
        for (int ch = 0; ch < 2; ++ch)
            #pragma unroll
            for (int j = 0; j < 8; ++j) {
                const int k = ch * 32 + q * 8 + j;
                w11v[ch * 8 + j] = W1[k * 3 + 1];
                A1v[ch * 8 + j]  = fmaf(xs, W1[k * 3 + 0],
                                        fmaf(c0s, W1[k * 3 + 2], b1[k]));
            }
    }
    __syncthreads();

    const int srcA = ((q & 1) * 2) * 16 + cc;
    const int srcB = srcA + 16;
    const bool hiT = (q >> 1) != 0;

    float y = 0.0f;

    for (int step = 0; step < 50; ++step) {
        asm volatile("" ::: "memory");   // pin per-step LDS reads (no HW cost)
        // ---- layer 1 (fp32) -> split B1 fragments ----
        U8 B1h[2], B1l[2];
        #pragma unroll
        for (int ch = 0; ch < 2; ++ch)
            #pragma unroll
            for (int jp = 0; jp < 4; ++jp) {
                const int j0 = jp * 2, j1 = jp * 2 + 1;
                const float w0 = w11v[ch * 8 + j0];
                const float w1 = w11v[ch * 8 + j1];
                const float z0 = fmaf(y, w0, A1v[ch * 8 + j0]);
                const float z1 = fmaf(y, w1, A1v[ch * 8 + j1]);
                const float v0 = fwd ? fmaxf(z0, 0.f) : (z0 > 0.f ? w0 : 0.f);
                const float v1 = fwd ? fmaxf(z1, 0.f) : (z1 > 0.f ? w1 : 0.f);
                const unsigned hp = pkrtz(v0, v1);
                B1h[ch].u[jp] = hp;
                B1l[ch].u[jp] = pkrtz(lo0(hp, v0), lo1(hp, v1));
            }
        // ---- layer 2: split MFMA ----
        f32x4 ZH[4], ZL[4];
        #pragma unroll
        for (int T = 0; T < 4; ++T) {
            f32x4 aH;
            aH[0] = b2m[T * 4 + 0]; aH[1] = b2m[T * 4 + 1];
            aH[2] = b2m[T * 4 + 2]; aH[3] = b2m[T * 4 + 3];
            aH = __builtin_amdgcn_mfma_f32_16x16x32_f16(W2h[T][0], B1h[0].v, aH, 0, 0, 0);
            aH = __builtin_amdgcn_mfma_f32_16x16x32_f16(W2h[T][1], B1h[1].v, aH, 0, 0, 0);
            f32x4 aL = {0.f, 0.f, 0.f, 0.f};
            aL = __builtin_amdgcn_mfma_f32_16x16x32_f16(W2h[T][0], B1l[0].v, aL, 0, 0, 0);
            aL = __builtin_amdgcn_mfma_f32_16x16x32_f16(W2h[T][1], B1l[1].v, aL, 0, 0, 0);
            const f16x8 l0 = WL2f[T * 2 + 0][lane];
            const f16x8 l1 = WL2f[T * 2 + 1][lane];
            aL = __builtin_amdgcn_mfma_f32_16x16x32_f16(l0, B1h[0].v, aL, 0, 0, 0);
            aL = __builtin_amdgcn_mfma_f32_16x16x32_f16(l1, B1h[1].v, aL, 0, 0, 0);
            ZH[T] = aH; ZL[T] = aL;
        }
        // ---- combine + mask + split + C->B shfl transform ----
        unsigned pkh[4][2], pkl[4][2];
        #pragma unroll
        for (int T = 0; T < 4; ++T) {
            float v4[4];
            #pragma unroll
            for (int r = 0; r < 4; ++r) {
                const float z = fmaf(ZL[T][r], LOINV, ZH[T][r]);
                const float recv = __shfl_xor(z, 8);
                v4[r] = fwd ? fmaxf(z, 0.f) : (recv > 0.f ? z : 0.f);
            }
            const unsigned h0 = pkrtz(v4[0], v4[1]);
            const unsigned h1 = pkrtz(v4[2], v4[3]);
            pkh[T][0] = h0; pkh[T][1] = h1;
            pkl[T][0] = pkrtz(lo0(h0, v4[0]), lo1(h0, v4[1]));
            pkl[T][1] = pkrtz(lo0(h1, v4[2]), lo1(h1, v4[3]));
        }
        U8 B2h[2], B2l[2];
        #pragma unroll
        for (int ch = 0; ch < 2; ++ch)
            #pragma unroll
            for (int p = 0; p < 2; ++p) {
                const unsigned haL = (unsigned)__shfl((int)pkh[ch * 2][p],     srcA);
                const unsigned haH = (unsigned)__shfl((int)pkh[ch * 2 + 1][p], srcA);
                const unsigned hbL = (unsigned)__shfl((int)pkh[ch * 2][p],     srcB);
                const unsigned hbH = (unsigned)__shfl((int)pkh[ch * 2 + 1][p], srcB);
                const unsigned laL = (unsigned)__shfl((int)pkl[ch * 2][p],     srcA);
                const unsigned laH = (unsigned)__shfl((int)pkl[ch * 2 + 1][p], srcA);
                const unsigned lbL = (unsigned)__shfl((int)pkl[ch * 2][p],     srcB);
                const unsigned lbH = (unsigned)__shfl((int)pkl[ch * 2 + 1][p], srcB);
                B2h[ch].u[p]     = hiT ? haH : haL;
                B2h[ch].u[2 + p] = hiT ? hbH : hbL;
                B2l[ch].u[p]     = hiT ? laH : laL;
                B2l[ch].u[2 + p] = hiT ? lbH : lbL;
            }
        // ---- layer 3: split MFMA ----
        #pragma unroll
        for (int T = 0; T < 4; ++T) {
            f32x4 aH;
            aH[0] = b3m[T * 4 + 0]; aH[1] = b3m[T * 4 + 1];
            aH[2] = b3m[T * 4 + 2]; aH[3] = b3m[T * 4 + 3];
            aH = __builtin_amdgcn_mfma_f32_16x16x32_f16(W3h[T][0], B2h[0].v, aH, 0, 0, 0);
            aH = __builtin_amdgcn_mfma_f32_16x16x32_f16(W3h[T][1], B2h[1].v, aH, 0, 0, 0);
            f32x4 aL = {0.f, 0.f, 0.f, 0.f};
            aL = __builtin_amdgcn_mfma_f32_16x16x32_f16(W3h[T][0], B2l[0].v, aL, 0, 0, 0);
            aL = __builtin_amdgcn_mfma_f32_16x16x32_f16(W3h[T][1], B2l[1].v, aL, 0, 0, 0);
            const f16x8 l0 = WL3f[T * 2 + 0][lane];
            const f16x8 l1 = WL3f[T * 2 + 1][lane];
            aL = __builtin_amdgcn_mfma_f32_16x16x32_f16(l0, B2h[0].v, aL, 0, 0, 0);
            aL = __builtin_amdgcn_mfma_f32_16x16x32_f16(l1, B2h[1].v, aL, 0, 0, 0);
            ZH[T] = aH; ZL[T] = aL;
        }
        // ---- layer 4 (fp32): g = W4 . (1[z3>0] * dz3) ----
        float g = 0.f;
        #pragma unroll
        for (int T = 0; T < 4; ++T)
            #pragma unroll
            for (int r = 0; r < 4; ++r) {
                const float z = fmaf(ZL[T][r], LOINV, ZH[T][r]);
                const float recv  = __shfl_xor(z, 8);
                const float maskv = fwd ? z : recv;
                const float valv  = fwd ? recv : z;
                g = fmaf(w4r[T * 4 + r], (maskv > 0.f) ? valv : 0.f, g);
            }
        g += __shfl_xor(g, 16);
        g += __shfl_xor(g, 32);
        y -= 0.1f * g;
    }
    if (lane < 4) out[sbase + lane] = y;
}

extern "C" void kernel_launch(void* const* d_in, const int* in_sizes, int n_in,
                              void* d_out, int out_size, void* d_ws, size_t ws_size,
                              hipStream_t stream) {
    const float* x  = (const float*)d_in[0];
    const float* c  = (const float*)d_in[1];
    const float* W1 = (const float*)d_in[2];
    const float* b1 = (const float*)d_in[3];
    const float* W2 = (const float*)d_in[4];
    const float* b2 = (const float*)d_in[5];
    const float* W3 = (const float*)d_in[6];
    const float* b3 = (const float*)d_in[7];
    const float* W4 = (const float*)d_in[8];
    // d_in[9] = b4: unused (only grad wrt y is needed, b4 drops out)
    float* c0  = (float*)d_ws;
    float* out = (float*)d_out;

    nn_kernel<<<BATCH / 8, 256, 0, stream>>>(c, c0);
    solve_kernel<<<BATCH / 4, 64, 0, stream>>>(x, c0, W1, b1, W2, b2, W3, b3, W4, out);
}

// Round 7
// 168.632 us; speedup vs baseline: 1.2375x; 1.2375x over previous
//
#include <hip/hip_runtime.h>

#define BATCH 8192
#define LOSC  2048.0f
#define LOINV (1.0f / 2048.0f)

typedef _Float16 f16x4 __attribute__((ext_vector_type(4)));
typedef __fp16   fp16x2 __attribute__((ext_vector_type(2)));
typedef float    f32x4 __attribute__((ext_vector_type(4)));

union PK2 { fp16x2 h; unsigned u; };
union U4  { f16x4 v; unsigned u[2]; };

// pack two f32 -> 2 f16 via v_cvt_pkrtz (RTZ is fine for hi/lo splitting:
// any hi with |v-hi| <= ulp works; lo carries the remainder, scaled 2^11)
__device__ __forceinline__ unsigned pkrtz(float a, float b) {
    PK2 p; p.h = __builtin_amdgcn_cvt_pkrtz(a, b); return p.u;
}
__device__ __forceinline__ float lo0(unsigned hp, float v) {
    PK2 p; p.u = hp; return (v - (float)p.h[0]) * LOSC;
}
__device__ __forceinline__ float lo1(unsigned hp, float v) {
    PK2 p; p.u = hp; return (v - (float)p.h[1]) * LOSC;
}

// ---------------------------------------------------------------------------
// Kernel 1: exact NN (CD=1). Reference distance sqrt(fl(dx*dx)) == |dx| in
// correctly-rounded fp32 -> compare fabsf(dx); first-index argmin preserved
// (strict < over ascending j), self excluded.
// ---------------------------------------------------------------------------
__global__ __launch_bounds__(256) void nn_kernel(const float* __restrict__ c,
                                                 float* __restrict__ c0) {
    __shared__ float cs[BATCH];
    const int t = threadIdx.x;
    {
        const float4* cg = (const float4*)c;
        float4* cl = (float4*)cs;
        for (int j = t; j < BATCH / 4; j += 256) cl[j] = cg[j];
    }
    __syncthreads();
    const int part = t & 31;
    const int i    = blockIdx.x * 8 + (t >> 5);
    const float ci = cs[i];
    const int sj0 = ((i & 3) == 0) ? (i >> 2) : -1;
    const int sj1 = ((i & 3) == 1) ? (i >> 2) : -1;
    const int sj2 = ((i & 3) == 2) ? (i >> 2) : -1;
    const int sj3 = ((i & 3) == 3) ? (i >> 2) : -1;
    const float4* cs4 = (const float4*)cs;
    float bd0 = 3e38f, bd1 = 3e38f, bd2 = 3e38f, bd3 = 3e38f;
    int   bj0 = 0,     bj1 = 0,     bj2 = 0,     bj3 = 0;
    #pragma unroll 4
    for (int tt = 0; tt < 64; ++tt) {
        const int jj = part + (tt << 5);
        const float4 v = cs4[jj];
        float d0 = fabsf(ci - v.x);
        float d1 = fabsf(ci - v.y);
        float d2 = fabsf(ci - v.z);
        float d3 = fabsf(ci - v.w);
        if (jj == sj0) d0 = 3e38f;
        if (jj == sj1) d1 = 3e38f;
        if (jj == sj2) d2 = 3e38f;
        if (jj == sj3) d3 = 3e38f;
        if (d0 < bd0) { bd0 = d0; bj0 = jj; }
        if (d1 < bd1) { bd1 = d1; bj1 = jj; }
        if (d2 < bd2) { bd2 = d2; bj2 = jj; }
        if (d3 < bd3) { bd3 = d3; bj3 = jj; }
    }
    float best = bd0; int bestj = bj0 * 4 + 0;
    { const int j1 = bj1 * 4 + 1; if (bd1 < best || (bd1 == best && j1 < bestj)) { best = bd1; bestj = j1; } }
    { const int j2 = bj2 * 4 + 2; if (bd2 < best || (bd2 == best && j2 < bestj)) { best = bd2; bestj = j2; } }
    { const int j3 = bj3 * 4 + 3; if (bd3 < best || (bd3 == best && j3 < bestj)) { best = bd3; bestj = j3; } }
    #pragma unroll
    for (int off = 1; off < 32; off <<= 1) {
        const float od = __shfl_xor(best, off);
        const int   oj = __shfl_xor(bestj, off);
        if (od < best || (od == best && oj < bestj)) { best = od; bestj = oj; }
    }
    if (part == 0) c0[i] = cs[bestj];
}

// ---------------------------------------------------------------------------
// Kernel 2 (v7): 8 samples/wave, 1024 blocks x 1 wave (1 wave/SIMD — hard
// occupancy cap; R6 proved duplication loses). Split-f16 via
// mfma_f32_16x16x16_f16 (K=16): B k-mapping (k=q*4+j) == C/D row mapping
// (row=q*4+r), so C-tile T is B-chunk T PER-LANE — the inter-layer
// transform needs ZERO shfls. Everything (W hi+lo frags, biases) lives in
// registers; no LDS, no barriers, no in-loop memory.
// B cols = [8 fwd | 8 tangent]; masks via shfl_xor(.,8).
// ---------------------------------------------------------------------------
__global__ __launch_bounds__(64, 1) void solve_kernel(
    const float* __restrict__ x, const float* __restrict__ c0g,
    const float* __restrict__ W1, const float* __restrict__ b1,
    const float* __restrict__ W2, const float* __restrict__ b2,
    const float* __restrict__ W3, const float* __restrict__ b3,
    const float* __restrict__ W4, float* __restrict__ out)
{
    const int lane = threadIdx.x & 63;
    const int q  = lane >> 4;
    const int cc = lane & 15;
    const bool fwd = (cc < 8);
    const int s = cc & 7;
    const int sbase = blockIdx.x * 8;

    // ---- W2/W3 hi+lo fragments, all in registers ----
    // A-frag (T,m): lane holds W[(T*16+cc)][m*16 + q*4 + j], j=0..3 (float4)
    f16x4 W2h[4][4], W2l[4][4], W3h[4][4], W3l[4][4];
    #pragma unroll
    for (int T = 0; T < 4; ++T)
        #pragma unroll
        for (int m = 0; m < 4; ++m) {
            const int off = (T * 16 + cc) * 64 + m * 16 + q * 4;
            const float4 w2 = *(const float4*)(W2 + off);
            const float4 w3 = *(const float4*)(W3 + off);
            U4 h, l;
            h.u[0] = pkrtz(w2.x, w2.y); h.u[1] = pkrtz(w2.z, w2.w);
            l.u[0] = pkrtz(lo0(h.u[0], w2.x), lo1(h.u[0], w2.y));
            l.u[1] = pkrtz(lo0(h.u[1], w2.z), lo1(h.u[1], w2.w));
            W2h[T][m] = h.v; W2l[T][m] = l.v;
            h.u[0] = pkrtz(w3.x, w3.y); h.u[1] = pkrtz(w3.z, w3.w);
            l.u[0] = pkrtz(lo0(h.u[0], w3.x), lo1(h.u[0], w3.y));
            l.u[1] = pkrtz(lo0(h.u[1], w3.z), lo1(h.u[1], w3.w));
            W3h[T][m] = h.v; W3l[T][m] = l.v;
        }

    // ---- pre-masked biases + W4, C-layout rows T*16 + q*4 + r ----
    float b2m[16], b3m[16], w4r[16];
    #pragma unroll
    for (int T = 0; T < 4; ++T)
        #pragma unroll
        for (int r = 0; r < 4; ++r) {
            const int row = T * 16 + q * 4 + r;
            b2m[T * 4 + r] = fwd ? b2[row] : 0.f;
            b3m[T * 4 + r] = fwd ? b3[row] : 0.f;
            w4r[T * 4 + r] = W4[row];
        }

    // ---- layer-1 constants: B rows k = m*16 + q*4 + j ----
    float A1v[16], w11v[16];
    {
        const float xs  = x[sbase + s];
        const float c0s = c0g[sbase + s];
        #pragma unroll
        for (int m = 0; m < 4; ++m)
            #pragma unroll
            for (int j = 0; j < 4; ++j) {
                const int k = m * 16 + q * 4 + j;
                w11v[m * 4 + j] = W1[k * 3 + 1];
                A1v[m * 4 + j]  = fmaf(xs, W1[k * 3 + 0],
                                       fmaf(c0s, W1[k * 3 + 2], b1[k]));
            }
    }

    float y = 0.0f;

    #pragma unroll 1
    for (int step = 0; step < 50; ++step) {
        // ---- layer 1 (fp32, registers) -> split B1 chunks ----
        U4 B1h[4], B1l[4];
        #pragma unroll
        for (int m = 0; m < 4; ++m) {
            float v[4];
            #pragma unroll
            for (int j = 0; j < 4; ++j) {
                const float w = w11v[m * 4 + j];
                const float z = fmaf(y, w, A1v[m * 4 + j]);
                v[j] = fwd ? fmaxf(z, 0.f) : (z > 0.f ? w : 0.f);
            }
            const unsigned h0 = pkrtz(v[0], v[1]);
            const unsigned h1 = pkrtz(v[2], v[3]);
            B1h[m].u[0] = h0; B1h[m].u[1] = h1;
            B1l[m].u[0] = pkrtz(lo0(h0, v[0]), lo1(h0, v[1]));
            B1l[m].u[1] = pkrtz(lo0(h1, v[2]), lo1(h1, v[3]));
        }
        // ---- layer 2: split MFMA (K=16 x 4 chunks) ----
        f32x4 ZH[4], ZL[4];
        #pragma unroll
        for (int T = 0; T < 4; ++T) {
            f32x4 aH;
            aH[0] = b2m[T * 4 + 0]; aH[1] = b2m[T * 4 + 1];
            aH[2] = b2m[T * 4 + 2]; aH[3] = b2m[T * 4 + 3];
            f32x4 aL = {0.f, 0.f, 0.f, 0.f};
            #pragma unroll
            for (int m = 0; m < 4; ++m) {
                aH = __builtin_amdgcn_mfma_f32_16x16x16f16(W2h[T][m], B1h[m].v, aH, 0, 0, 0);
                aL = __builtin_amdgcn_mfma_f32_16x16x16f16(W2h[T][m], B1l[m].v, aL, 0, 0, 0);
                aL = __builtin_amdgcn_mfma_f32_16x16x16f16(W2l[T][m], B1h[m].v, aL, 0, 0, 0);
            }
            ZH[T] = aH; ZL[T] = aL;
        }
        // ---- combine + mask -> B2 chunks DIRECTLY (C-tile T == B-chunk T) ----
        U4 B2h[4], B2l[4];
        #pragma unroll
        for (int T = 0; T < 4; ++T) {
            float v[4];
            #pragma unroll
            for (int r = 0; r < 4; ++r) {
                const float z = fmaf(ZL[T][r], LOINV, ZH[T][r]);
                const float recv = __shfl_xor(z, 8);
                v[r] = fwd ? fmaxf(z, 0.f) : (recv > 0.f ? z : 0.f);
            }
            const unsigned h0 = pkrtz(v[0], v[1]);
            const unsigned h1 = pkrtz(v[2], v[3]);
            B2h[T].u[0] = h0; B2h[T].u[1] = h1;
            B2l[T].u[0] = pkrtz(lo0(h0, v[0]), lo1(h0, v[1]));
            B2l[T].u[1] = pkrtz(lo0(h1, v[2]), lo1(h1, v[3]));
        }
        // ---- layer 3: split MFMA ----
        #pragma unroll
        for (int T = 0; T < 4; ++T) {
            f32x4 aH;
            aH[0] = b3m[T * 4 + 0]; aH[1] = b3m[T * 4 + 1];
            aH[2] = b3m[T * 4 + 2]; aH[3] = b3m[T * 4 + 3];
            f32x4 aL = {0.f, 0.f, 0.f, 0.f};
            #pragma unroll
            for (int m = 0; m < 4; ++m) {
                aH = __builtin_amdgcn_mfma_f32_16x16x16f16(W3h[T][m], B2h[m].v, aH, 0, 0, 0);
                aL = __builtin_amdgcn_mfma_f32_16x16x16f16(W3h[T][m], B2l[m].v, aL, 0, 0, 0);
                aL = __builtin_amdgcn_mfma_f32_16x16x16f16(W3l[T][m], B2h[m].v, aL, 0, 0, 0);
            }
            ZH[T] = aH; ZL[T] = aL;
        }
        // ---- layer 4 (fp32): g = W4 . (1[z3>0] * dz3) ----
        float g = 0.f;
        #pragma unroll
        for (int T = 0; T < 4; ++T)
            #pragma unroll
            for (int r = 0; r < 4; ++r) {
                const float z = fmaf(ZL[T][r], LOINV, ZH[T][r]);
                const float recv  = __shfl_xor(z, 8);
                const float maskv = fwd ? z : recv;   // z3 fwd (with bias)
                const float valv  = fwd ? recv : z;   // dz3
                g = fmaf(w4r[T * 4 + r], (maskv > 0.f) ? valv : 0.f, g);
            }
        g += __shfl_xor(g, 16);   // sum over quads (bitwise-uniform per sample)
        g += __shfl_xor(g, 32);
        y -= 0.1f * g;
    }
    if (lane < 8) out[sbase + lane] = y;
}

extern "C" void kernel_launch(void* const* d_in, const int* in_sizes, int n_in,
                              void* d_out, int out_size, void* d_ws, size_t ws_size,
                              hipStream_t stream) {
    const float* x  = (const float*)d_in[0];
    const float* c  = (const float*)d_in[1];
    const float* W1 = (const float*)d_in[2];
    const float* b1 = (const float*)d_in[3];
    const float* W2 = (const float*)d_in[4];
    const float* b2 = (const float*)d_in[5];
    const float* W3 = (const float*)d_in[6];
    const float* b3 = (const float*)d_in[7];
    const float* W4 = (const float*)d_in[8];
    // d_in[9] = b4: unused (only grad wrt y is needed, b4 drops out)
    float* c0  = (float*)d_ws;
    float* out = (float*)d_out;

    nn_kernel<<<BATCH / 8, 256, 0, stream>>>(c, c0);
    solve_kernel<<<BATCH / 8, 64, 0, stream>>>(x, c0, W1, b1, W2, b2, W3, b3, W4, out);
}